// Round 1
// baseline (1570.757 us; speedup 1.0000x reference)
//
#include <hip/hip_runtime.h>

typedef _Float16 half8 __attribute__((ext_vector_type(8)));
typedef float floatx16 __attribute__((ext_vector_type(16)));

#define TPB   256            // 4 waves
#define RPTS  512            // db points staged per round (per buffer)
#define PPT   (RPTS / TPB)   // 2 points per thread per round
#define NTILE (RPTS / 32)    // 16 tiles of 32 db points
#define SMH   (RPTS * 16)    // 8192 halfs = 16 KiB per buffer

// 32x32x16 f16 MFMA formulation. Each wave owns 64 queries (2 A-frags x 32 rows);
// block = 256 queries. db double-buffered in rounds of 512 points as pre-formatted
// B-fragments; staging is software-pipelined two rounds deep:
//   round r: issue global loads for r+2 -> regs; ds_write regs(r+1) -> buf[cur^1];
//            sweep buf[cur]; ONE barrier.
// K-slots (11 of 16 used):
//   B: (xh, xl, xh, yh, yl, yh, zh, zl | zh, hqh, hql, 0..)
//   A: (-xh,-xh,-xl,-yh,-yh,-yl,-zh,-zh | -zl, 1, 1, 0..)
// => acc = 0.5||q||^2 - p.q (split-f16, abs err ~5e-5);  dist = 2*(ph + min acc).
// A layout: row m = lane&31, k = (lane>>5)*8 + j.  B: col c = lane&31, same k.
// C/D: col = lane&31, row = (reg&3) + 8*(reg>>2) + 4*(lane>>5).
__global__ __launch_bounds__(TPB, 4) void chamfer_mfma(const float* __restrict__ xyz1,
                                                       const float* __restrict__ xyz2,
                                                       float* __restrict__ out,
                                                       int N, int M) {
    const int b = blockIdx.y, dir = blockIdx.z;
    const float* __restrict__ P = dir ? xyz2 + (size_t)b * M * 3 : xyz1 + (size_t)b * N * 3;
    const float* __restrict__ Q = dir ? xyz1 + (size_t)b * N * 3 : xyz2 + (size_t)b * M * 3;
    const int nq = dir ? M : N;
    const int md = dir ? N : M;

    if ((int)blockIdx.x * TPB >= nq) return;   // block-uniform, before any barrier

    __shared__ __align__(16) _Float16 smB[2][SMH];

    const int tid = (int)threadIdx.x;
    const int w   = tid >> 6;
    const int l   = tid & 63;
    const int m   = l & 31;      // A row / B col this lane serves
    const int h   = l >> 5;      // k-half: k = h*8 + j

    const _Float16 hz = (_Float16)0.0f, hone = (_Float16)1.0f;
    const int qb = blockIdx.x * 256 + w * 64;

    // ---- Build the wave's 2 A-fragments (held for the whole kernel) ----
    half8 afr[2];
#pragma unroll
    for (int g = 0; g < 2; ++g) {
        int idx = qb + g * 32 + m;
        int ci  = idx < nq ? idx : nq - 1;
        float x = P[3 * ci], y = P[3 * ci + 1], z = P[3 * ci + 2];
        _Float16 xh = (_Float16)x, yh = (_Float16)y, zh = (_Float16)z;
        _Float16 xl = (_Float16)(x - (float)xh);
        _Float16 yl = (_Float16)(y - (float)yh);
        _Float16 zl = (_Float16)(z - (float)zh);
        half8 a;
        if (h == 0) {
            a[0] = -xh; a[1] = -xh; a[2] = -xl; a[3] = -yh;
            a[4] = -yh; a[5] = -yl; a[6] = -zh; a[7] = -zh;
        } else {
            a[0] = -zl; a[1] = hone; a[2] = hone; a[3] = hz;
            a[4] = hz;  a[5] = hz;   a[6] = hz;  a[7] = hz;
        }
        afr[g] = a;
    }

    // ---- staging helpers ----
    auto ldpts = [&](int r, float* px, float* py, float* pz) {
#pragma unroll
        for (int k = 0; k < PPT; ++k) {
            int g = r * RPTS + tid + k * TPB;
            g = g < md ? g : md - 1;              // clamp-pad: dups never change a min
            px[k] = Q[3 * g];
            py[k] = Q[3 * g + 1];
            pz[k] = Q[3 * g + 2];
        }
    };
    auto wrpts = [&](int buf, const float* px, const float* py, const float* pz) {
#pragma unroll
        for (int k = 0; k < PPT; ++k) {
            int j = tid + k * TPB;
            float x = px[k], y = py[k], z = pz[k];
            float hq = 0.5f * (x * x + y * y + z * z);
            _Float16 xh = (_Float16)x, yh = (_Float16)y, zh = (_Float16)z;
            _Float16 xl = (_Float16)(x - (float)xh);
            _Float16 yl = (_Float16)(y - (float)yh);
            _Float16 zl = (_Float16)(z - (float)zh);
            _Float16 qh = (_Float16)hq;
            _Float16 ql = (_Float16)(hq - (float)qh);
            int t = j >> 5, c = j & 31;
            half8 v0, v1;
            v0[0] = xh; v0[1] = xl; v0[2] = xh; v0[3] = yh;
            v0[4] = yl; v0[5] = yh; v0[6] = zh; v0[7] = zl;
            v1[0] = zh; v1[1] = qh; v1[2] = ql; v1[3] = hz;
            v1[4] = hz; v1[5] = hz; v1[6] = hz; v1[7] = hz;
            *(half8*)&smB[buf][t * 512 + c * 8]       = v0;   // k-half 0
            *(half8*)&smB[buf][t * 512 + 256 + c * 8] = v1;   // k-half 1
        }
    };

    float rm[32];
#pragma unroll
    for (int i = 0; i < 32; ++i) rm[i] = 3.0e38f;

    const floatx16 czero = {0.0f, 0.0f, 0.0f, 0.0f, 0.0f, 0.0f, 0.0f, 0.0f,
                            0.0f, 0.0f, 0.0f, 0.0f, 0.0f, 0.0f, 0.0f, 0.0f};
    const int nrounds = (md + RPTS - 1) / RPTS;

    // ---- prologue: fill buf0 with round 0; hold round 1 in regs (set A) ----
    float pxA[PPT], pyA[PPT], pzA[PPT];
    float pxB[PPT], pyB[PPT], pzB[PPT];
    ldpts(0, pxA, pyA, pzA);
    wrpts(0, pxA, pyA, pzA);
    if (nrounds > 1) ldpts(1, pxA, pyA, pzA);   // A now holds round-1 data
    __syncthreads();

    const _Float16* bp0 = &smB[0][h * 256 + m * 8];
    const _Float16* bp1 = &smB[1][h * 256 + m * 8];

    int cur = 0;
    for (int r = 0; r < nrounds; ++r) {
        // ---- pipelined staging: write r+1 now, issue loads for r+2 ----
        if (r + 1 < nrounds) {
            if ((r & 1) == 0) {
                if (r + 2 < nrounds) ldpts(r + 2, pxB, pyB, pzB);
                wrpts(cur ^ 1, pxA, pyA, pzA);
            } else {
                if (r + 2 < nrounds) ldpts(r + 2, pxA, pyA, pzA);
                wrpts(cur ^ 1, pxB, pyB, pzB);
            }
        }

        // ---- Sweep: 16 tiles, 2 per iteration; min3 fold (fully unrolled) ----
        const _Float16* bp = cur ? bp1 : bp0;
#pragma unroll
        for (int t = 0; t < NTILE; t += 2) {
            half8 b0 = *(const half8*)(bp + t * 512);
            half8 b1 = *(const half8*)(bp + t * 512 + 512);
            floatx16 d0a = __builtin_amdgcn_mfma_f32_32x32x16_f16(afr[0], b0, czero, 0, 0, 0);
            floatx16 d0b = __builtin_amdgcn_mfma_f32_32x32x16_f16(afr[0], b1, czero, 0, 0, 0);
#pragma unroll
            for (int i = 0; i < 16; ++i)
                rm[i] = fminf(fminf(rm[i], d0a[i]), d0b[i]);         // -> v_min3
            floatx16 d1a = __builtin_amdgcn_mfma_f32_32x32x16_f16(afr[1], b0, czero, 0, 0, 0);
            floatx16 d1b = __builtin_amdgcn_mfma_f32_32x32x16_f16(afr[1], b1, czero, 0, 0, 0);
#pragma unroll
            for (int i = 0; i < 16; ++i)
                rm[16 + i] = fminf(fminf(rm[16 + i], d1a[i]), d1b[i]);
        }

        if (r + 1 < nrounds) __syncthreads();   // uniform condition; last round skips
        cur ^= 1;
    }

    // ---- Col-min across the 32 lanes of each k-half (rows identical per half) ----
#pragma unroll
    for (int off = 1; off < 32; off <<= 1) {
#pragma unroll
        for (int i = 0; i < 32; ++i) rm[i] = fminf(rm[i], __shfl_xor(rm[i], off, 64));
    }

    // ---- Emit: lanes c<16 of each half own one row each; recompute ph from P ----
    float s = 0.0f;
    if (m < 16) {
        const int reg = (m & 3) + 4 * (m >> 2);
        const int row = 4 * h + (m & 3) + 8 * (m >> 2);
#pragma unroll
        for (int g = 0; g < 2; ++g) {
            int idx = qb + g * 32 + row;
            if (idx < nq) {
                float x = P[3 * idx], y = P[3 * idx + 1], z = P[3 * idx + 2];
                s += rm[g * 16 + reg] + 0.5f * (x * x + y * y + z * z);
            }
        }
    }
#pragma unroll
    for (int off = 32; off > 0; off >>= 1) s += __shfl_down(s, off, 64);
    if (l == 0) atomicAdd(out + b, s * (2.0f / (float)nq));   // dist = 2*(ph+acc)
}

extern "C" void kernel_launch(void* const* d_in, const int* in_sizes, int n_in,
                              void* d_out, int out_size, void* d_ws, size_t ws_size,
                              hipStream_t stream) {
    const float* xyz1 = (const float*)d_in[0];
    const float* xyz2 = (const float*)d_in[1];
    float* out = (float*)d_out;

    const int B = out_size;
    const int N = in_sizes[0] / (3 * B);
    const int M = in_sizes[1] / (3 * B);

    hipMemsetAsync(d_out, 0, (size_t)B * sizeof(float), stream);

    const int qmax = N > M ? N : M;
    dim3 grid((qmax + 255) / 256, B, 2);
    chamfer_mfma<<<grid, dim3(TPB), 0, stream>>>(xyz1, xyz2, out, N, M);
}

// Round 2
// 122.435 us; speedup vs baseline: 12.8293x; 12.8293x over previous
//
#include <hip/hip_runtime.h>

typedef _Float16 half8 __attribute__((ext_vector_type(8)));
typedef float floatx16 __attribute__((ext_vector_type(16)));

#define TPB   256            // 4 waves
#define RPTS  512            // db points staged per round (per buffer)
#define NTILE (RPTS / 32)    // 16 tiles of 32 db points
#define SMH   (RPTS * 16)    // 8192 halfs = 16 KiB per buffer

// 32x32x16 f16 MFMA formulation. Each wave owns 64 queries (2 A-frags x 32 rows);
// block = 256 queries. db double-buffered in rounds of 512 points as pre-formatted
// B-fragments. Pipeline (2-deep, ONE barrier per round):
//   round r: ds_write regs(r+1) -> buf[cur^1]; issue loads(r+2) -> regs;
//            sweep buf[cur]; __syncthreads().
// Staging data lives in SIX NAMED SCALARS (sx0..sz1) — never an array, never
// address-taken: round-1's pointer-lambda version demoted rm[] to scratch
// (3.8 GB scratch writes, 13x regression).
// K-slots (11 of 16 used):
//   B: (xh, xl, xh, yh, yl, yh, zh, zl | zh, hqh, hql, 0..)
//   A: (-xh,-xh,-xl,-yh,-yh,-yl,-zh,-zh | -zl, 1, 1, 0..)
// => acc = 0.5||q||^2 - p.q (split-f16, abs err ~5e-5);  dist = 2*(ph + min acc).
// A layout: row m = lane&31, k = (lane>>5)*8 + j.  B: col c = lane&31, same k.
// C/D: col = lane&31, row = (reg&3) + 8*(reg>>2) + 4*(lane>>5).

__device__ __forceinline__ void wr_point(_Float16* __restrict__ smb, int j,
                                         float x, float y, float z) {
    float hq = 0.5f * (x * x + y * y + z * z);
    _Float16 xh = (_Float16)x, yh = (_Float16)y, zh = (_Float16)z;
    _Float16 xl = (_Float16)(x - (float)xh);
    _Float16 yl = (_Float16)(y - (float)yh);
    _Float16 zl = (_Float16)(z - (float)zh);
    _Float16 qh = (_Float16)hq;
    _Float16 ql = (_Float16)(hq - (float)qh);
    const _Float16 hz = (_Float16)0.0f;
    int t = j >> 5, c = j & 31;
    half8 v0, v1;
    v0[0] = xh; v0[1] = xl; v0[2] = xh; v0[3] = yh;
    v0[4] = yl; v0[5] = yh; v0[6] = zh; v0[7] = zl;
    v1[0] = zh; v1[1] = qh; v1[2] = ql; v1[3] = hz;
    v1[4] = hz; v1[5] = hz; v1[6] = hz; v1[7] = hz;
    *(half8*)&smb[t * 512 + c * 8]       = v0;   // k-half 0
    *(half8*)&smb[t * 512 + 256 + c * 8] = v1;   // k-half 1
}

__global__ __launch_bounds__(TPB, 4) void chamfer_mfma(const float* __restrict__ xyz1,
                                                       const float* __restrict__ xyz2,
                                                       float* __restrict__ out,
                                                       int N, int M) {
    const int b = blockIdx.y, dir = blockIdx.z;
    const float* __restrict__ P = dir ? xyz2 + (size_t)b * M * 3 : xyz1 + (size_t)b * N * 3;
    const float* __restrict__ Q = dir ? xyz1 + (size_t)b * N * 3 : xyz2 + (size_t)b * M * 3;
    const int nq = dir ? M : N;
    const int md = dir ? N : M;

    if ((int)blockIdx.x * TPB >= nq) return;   // block-uniform, before any barrier

    __shared__ __align__(16) _Float16 smB[2][SMH];

    const int tid = (int)threadIdx.x;
    const int w   = tid >> 6;
    const int l   = tid & 63;
    const int m   = l & 31;      // A row / B col this lane serves
    const int h   = l >> 5;      // k-half: k = h*8 + j

    const _Float16 hz = (_Float16)0.0f, hone = (_Float16)1.0f;
    const int qb = blockIdx.x * 256 + w * 64;

    // ---- Build the wave's 2 A-fragments (held for the whole kernel) ----
    half8 afr[2];
#pragma unroll
    for (int g = 0; g < 2; ++g) {
        int idx = qb + g * 32 + m;
        int ci  = idx < nq ? idx : nq - 1;
        float x = P[3 * ci], y = P[3 * ci + 1], z = P[3 * ci + 2];
        _Float16 xh = (_Float16)x, yh = (_Float16)y, zh = (_Float16)z;
        _Float16 xl = (_Float16)(x - (float)xh);
        _Float16 yl = (_Float16)(y - (float)yh);
        _Float16 zl = (_Float16)(z - (float)zh);
        half8 a;
        if (h == 0) {
            a[0] = -xh; a[1] = -xh; a[2] = -xl; a[3] = -yh;
            a[4] = -yh; a[5] = -yl; a[6] = -zh; a[7] = -zh;
        } else {
            a[0] = -zl; a[1] = hone; a[2] = hone; a[3] = hz;
            a[4] = hz;  a[5] = hz;   a[6] = hz;  a[7] = hz;
        }
        afr[g] = a;
    }

    // ---- staging registers: named scalars ONLY (see header comment) ----
    float sx0, sy0, sz0, sx1, sy1, sz1;
#define LDPTS(rr) {                                                   \
        int g0 = (rr) * RPTS + tid;                                   \
        int g1 = g0 + TPB;                                            \
        g0 = g0 < md ? g0 : md - 1;  /* clamp-pad: dups never change a min */ \
        g1 = g1 < md ? g1 : md - 1;                                   \
        sx0 = Q[3 * g0]; sy0 = Q[3 * g0 + 1]; sz0 = Q[3 * g0 + 2];    \
        sx1 = Q[3 * g1]; sy1 = Q[3 * g1 + 1]; sz1 = Q[3 * g1 + 2];    \
    }
#define WRPTS(bb) {                                                   \
        wr_point(&smB[bb][0], tid,       sx0, sy0, sz0);              \
        wr_point(&smB[bb][0], tid + TPB, sx1, sy1, sz1);              \
    }

    float rm[32];
#pragma unroll
    for (int i = 0; i < 32; ++i) rm[i] = 3.0e38f;

    const floatx16 czero = {0.0f, 0.0f, 0.0f, 0.0f, 0.0f, 0.0f, 0.0f, 0.0f,
                            0.0f, 0.0f, 0.0f, 0.0f, 0.0f, 0.0f, 0.0f, 0.0f};
    const int nrounds = (md + RPTS - 1) / RPTS;

    // ---- prologue: buf0 <- round 0; regs <- round 1 ----
    LDPTS(0);
    WRPTS(0);
    if (nrounds > 1) LDPTS(1);
    __syncthreads();

    const _Float16* bp0 = &smB[0][h * 256 + m * 8];
    const _Float16* bp1 = &smB[1][h * 256 + m * 8];

    int cur = 0;
    for (int r = 0; r < nrounds; ++r) {
        // write regs(r+1) -> other buffer (safe: it was last swept in r-1,
        // and the barrier at end of r-1 cleared it); then issue loads for r+2.
        if (r + 1 < nrounds) {
            WRPTS(cur ^ 1);
            if (r + 2 < nrounds) LDPTS(r + 2);
        }

        // ---- Sweep buf[cur]: 16 tiles, 2 per iteration; min3 fold ----
        const _Float16* bp = cur ? bp1 : bp0;
        for (int t = 0; t < NTILE; t += 2) {
            half8 b0 = *(const half8*)(bp + t * 512);
            half8 b1 = *(const half8*)(bp + t * 512 + 512);
            floatx16 d0a = __builtin_amdgcn_mfma_f32_32x32x16_f16(afr[0], b0, czero, 0, 0, 0);
            floatx16 d0b = __builtin_amdgcn_mfma_f32_32x32x16_f16(afr[0], b1, czero, 0, 0, 0);
#pragma unroll
            for (int i = 0; i < 16; ++i)
                rm[i] = fminf(fminf(rm[i], d0a[i]), d0b[i]);         // -> v_min3
            floatx16 d1a = __builtin_amdgcn_mfma_f32_32x32x16_f16(afr[1], b0, czero, 0, 0, 0);
            floatx16 d1b = __builtin_amdgcn_mfma_f32_32x32x16_f16(afr[1], b1, czero, 0, 0, 0);
#pragma unroll
            for (int i = 0; i < 16; ++i)
                rm[16 + i] = fminf(fminf(rm[16 + i], d1a[i]), d1b[i]);
        }

        if (r + 1 < nrounds) __syncthreads();   // uniform; last round skips
        cur ^= 1;
    }

    // ---- Col-min across the 32 lanes of each k-half (rows identical per half) ----
#pragma unroll
    for (int off = 1; off < 32; off <<= 1) {
#pragma unroll
        for (int i = 0; i < 32; ++i) rm[i] = fminf(rm[i], __shfl_xor(rm[i], off, 64));
    }

    // ---- Emit: lanes c<16 of each half own one row each; recompute ph from P ----
    float s = 0.0f;
    if (m < 16) {
        const int reg = (m & 3) + 4 * (m >> 2);
        const int row = 4 * h + (m & 3) + 8 * (m >> 2);
#pragma unroll
        for (int g = 0; g < 2; ++g) {
            int idx = qb + g * 32 + row;
            if (idx < nq) {
                float x = P[3 * idx], y = P[3 * idx + 1], z = P[3 * idx + 2];
                s += rm[g * 16 + reg] + 0.5f * (x * x + y * y + z * z);
            }
        }
    }
#pragma unroll
    for (int off = 32; off > 0; off >>= 1) s += __shfl_down(s, off, 64);
    if (l == 0) atomicAdd(out + b, s * (2.0f / (float)nq));   // dist = 2*(ph+acc)
}

extern "C" void kernel_launch(void* const* d_in, const int* in_sizes, int n_in,
                              void* d_out, int out_size, void* d_ws, size_t ws_size,
                              hipStream_t stream) {
    const float* xyz1 = (const float*)d_in[0];
    const float* xyz2 = (const float*)d_in[1];
    float* out = (float*)d_out;

    const int B = out_size;
    const int N = in_sizes[0] / (3 * B);
    const int M = in_sizes[1] / (3 * B);

    hipMemsetAsync(d_out, 0, (size_t)B * sizeof(float), stream);

    const int qmax = N > M ? N : M;
    dim3 grid((qmax + 255) / 256, B, 2);
    chamfer_mfma<<<grid, dim3(TPB), 0, stream>>>(xyz1, xyz2, out, N, M);
}